// Round 10
// baseline (312.850 us; speedup 1.0000x reference)
//
#include <hip/hip_runtime.h>
#include <hip/hip_bf16.h>
#include <stdint.h>

#define B_   16
#define C_   256
#define H_   64
#define W_   64
#define PH   66
#define PW   66
#define K1   2304   // 256*9
#define NO1  256
#define NO2  128

typedef signed char i8;
typedef int   int32x4 __attribute__((ext_vector_type(4)));

__device__ __forceinline__ void gl_lds16(const void* src, void* dst) {
    __builtin_amdgcn_global_load_lds(
        (const __attribute__((address_space(1))) unsigned int*)src,
        (__attribute__((address_space(3))) unsigned int*)dst, 16, 0, 0);
}

__device__ __forceinline__ i8 sign_i8(float v) {
    return (v > 0.f) ? (i8)1 : ((v < 0.f) ? (i8)(-1) : (i8)0);
}

// ---------------- prep s1: sign(x + bias1_) -> padded NHWC i8 + halo zero -----
// Fused border zeroing for BOTH s1 and s2 (replaces halo_zero kernel).
__global__ void prep_s1(const float* __restrict__ x, const float* __restrict__ bias1_,
                        i8* __restrict__ s1, i8* __restrict__ s2) {
    __shared__ i8 tile[64][272];           // [w][c], stride 272 (17*16) to spread banks
    int b = blockIdx.x >> 6;
    int h = blockIdx.x & 63;
    int t = threadIdx.x;
    int w  = t & 63;
    int cq = t >> 6;                       // 0..3 (channel quarter)
    for (int i = 0; i < 64; ++i) {
        int c = cq * 64 + i;
        float v = x[((size_t)(b * C_ + c) * H_ + h) * W_ + w] + bias1_[c];
        tile[w][c] = sign_i8(v);
    }
    __syncthreads();
    for (int i = 0; i < 4; ++i) {
        int idx = i * 256 + t;
        int w2  = idx >> 4;                // 16 chunks per pixel
        int cb  = (idx & 15) * 16;
        int4 v = *(const int4*)&tile[w2][cb];
        *(int4*)(s1 + ((size_t)(b * PH + h + 1) * PW + (w2 + 1)) * C_ + cb) = v;
    }
    // ---- halo zeroing ----
    int4 z = make_int4(0, 0, 0, 0);
    // side borders of row h+1 for s1 and s2: (col 0) and (col 65), 16 chunks each
    if (t < 64) {
        int which = t >> 4;                // 0: s1 c0, 1: s1 c65, 2: s2 c0, 3: s2 c65
        int c16   = t & 15;
        i8* base  = (which < 2) ? s1 : s2;
        int col   = (which & 1) ? 65 : 0;
        *(int4*)(base + ((size_t)(b * PH + h + 1) * PW + col) * C_ + c16 * 16) = z;
    }
    // top row (ph=0) and bottom row (ph=65): zero full 66-pixel rows of s1 & s2
    if (h == 0 || h == 63) {
        int prow = (h == 0) ? 0 : 65;
        for (int i = 0; i < 9; ++i) {      // 2 tensors x 1056 chunks = 2112
            int idx = i * 256 + t;
            if (idx < 2112) {
                i8* base = (idx < 1056) ? s1 : s2;
                int k    = (idx < 1056) ? idx : idx - 1056;
                *(int4*)(base + ((size_t)(b * PH + prow) * PW) * C_ + k * 16) = z;
            }
        }
    }
}

// ---------------- prep weights: scale[o] and sign(w) transposed to [n][k] ------
// k ordering: k = tap*256 + c   (tap = dh*3+dw)
__global__ void prep_w(const float* __restrict__ w1, const float* __restrict__ w2,
                       const float* __restrict__ ka1, const float* __restrict__ kw1,
                       const float* __restrict__ ka2, const float* __restrict__ kw2,
                       i8* __restrict__ Bt1, i8* __restrict__ Bt2,
                       float* __restrict__ scale1, float* __restrict__ scale2) {
    int o = blockIdx.x;
    const float* w; i8* Bt; float* scale; float kk;
    if (o < NO1) { w = w1 + (size_t)o * K1;         Bt = Bt1 + (size_t)o * K1;         scale = scale1 + o;         kk = ka1[0] * kw1[0]; }
    else         { int oo = o - NO1;
                   w = w2 + (size_t)oo * K1;        Bt = Bt2 + (size_t)oo * K1;        scale = scale2 + oo;        kk = ka2[0] * kw2[0]; }
    int t = threadIdx.x;
    float s = 0.f;
    for (int e = t; e < K1; e += 256) {
        float v = w[e];
        s += fabsf(v);
        int c = e / 9, tap = e % 9;
        Bt[tap * 256 + c] = sign_i8(v);
    }
    for (int off = 32; off; off >>= 1) s += __shfl_down(s, off);
    __shared__ float red[4];
    if ((t & 63) == 0) red[t >> 6] = s;
    __syncthreads();
    if (t == 0) {
        float tot = red[0] + red[1] + red[2] + red[3];
        *scale = kk * tot * (1.0f / 2304.0f);
    }
}

// ---------------- A-resident, B-in-registers, barrier-free binary conv --------
// Block tile: BM=256 output rows (b, h0..h0+3, 64 w), BN=128 cols, K=2304.
// A (activations): entire 6x66x256 halo tile (101 KB) staged once to LDS
// (read-only after one prologue barrier; XOR-swizzled chunk^= pix&7).
// B (weights): per-wave register fragments loaded DIRECTLY from global
// (L1/L2-resident, addresses = per-thread base + compile-time ks*128 imm),
// double-buffered in two named register sets, issued one step ahead.
// -> the 18-step main loop has NO barriers and NO waitcnt drains; the 8 waves
// free-run and drift, hiding ds_read/L2 latency (fix for R8/R9's lockstep
// 5,300 cyc/step at 1 block/CU).
template<int EPI>
__device__ __forceinline__ void conv_body(
               char* Alds,
               const i8* __restrict__ Sin, const i8* __restrict__ Bt,
               const float* __restrict__ scale,
               const float* __restrict__ xaux,    // EPI1: x (NCHW f32); EPI2: xres_lo (NHWC 128 f32)
               const float* __restrict__ biasA,   // EPI1: bias2_ ; EPI2: bias3
               const float* __restrict__ bias4,   // EPI2 only
               const float* __restrict__ slope,   // EPI2 only
               i8*   __restrict__ s2out,          // EPI1 only
               float* __restrict__ xres_out,      // EPI1 only
               float* __restrict__ dout)          // EPI2 only
{
    int t  = threadIdx.x;

    // 1D grid + XCD chunk swizzle (T1): nwg % 8 == 0 -> bijective.
    int wg    = blockIdx.x;
    int chunk = gridDim.x >> 3;
    int logical = (wg & 7) * chunk + (wg >> 3);
    int nb, mb;
    if (EPI == 1) { nb = logical & 1; mb = logical >> 1; }
    else          { nb = 0;           mb = logical; }
    int b  = mb >> 4;
    int h0 = (mb & 15) * 4;        // output rows h0..h0+3

    int l  = t & 63;
    int wv = t >> 6;               // 0..7
    int wr = wv >> 1;              // 0..3 : wave M quarter (64 rows)
    int wc = wv & 1;               // 0..1 : wave N half   (64 cols)
    int q  = l >> 4;               // 0..3 : 16B slot within 64B k-group

    // ---- prologue: stage whole A tile (6336 x 16B chunks, swizzled source) ----
    for (int i = 0; i < 13; ++i) {
        int idx = i * 512 + t;
        if (idx < 6336) {
            int r6   = idx / 1056;             // padded row 0..5
            int rem  = idx - r6 * 1056;
            int w66  = rem >> 4;               // padded col 0..65
            int slot = rem & 15;
            int pix  = r6 * 66 + w66;
            const i8* ga = Sin + ((size_t)(b * PH + h0 + r6) * PW + w66) * 256
                               + ((slot ^ (pix & 7)) << 4);
            gl_lds16(ga, Alds + idx * 16);
        }
    }
    asm volatile("s_waitcnt vmcnt(0)" ::: "memory");
    __builtin_amdgcn_s_barrier();
    // A is read-only from here: no further barriers anywhere.

    // ---- per-thread constants ----
    int pixbase[4];
#pragma unroll
    for (int mi = 0; mi < 4; ++mi) {
        int m = wr * 64 + mi * 16 + (l & 15);
        pixbase[mi] = (m >> 6) * 66 + (m & 63);
    }
    const i8* bptr[4];
#pragma unroll
    for (int ni = 0; ni < 4; ++ni) {
        int n = nb * 128 + wc * 64 + ni * 16 + (l & 15);
        bptr[ni] = Bt + (size_t)n * K1 + q * 16;
    }

    int32x4 acc[4][4];
#pragma unroll
    for (int mi = 0; mi < 4; ++mi)
#pragma unroll
        for (int ni = 0; ni < 4; ++ni) acc[mi][ni] = (int32x4){0, 0, 0, 0};

    // B fragment loads: frag[ni*2+kk] = Bt row fragment at k-offset ks*128+kk*64
    auto loadB = [&](int ks, int32x4 (&dst)[8]) {
#pragma unroll
        for (int ni = 0; ni < 4; ++ni) {
            dst[ni * 2 + 0] = *(const int32x4*)(bptr[ni] + ks * 128);
            dst[ni * 2 + 1] = *(const int32x4*)(bptr[ni] + ks * 128 + 64);
        }
    };

    auto step = [&](int ks, const int32x4 (&bfr)[8]) {
        int tap  = ks >> 1;
        int toff = (tap / 3) * 66 + (tap % 3);
        int c8   = (ks & 1) << 7;
#pragma unroll
        for (int kk = 0; kk < 2; ++kk) {
            int qk = kk * 4 + q;
            int32x4 af[4];
#pragma unroll
            for (int mi = 0; mi < 4; ++mi) {
                int pixm = pixbase[mi] + toff;
                af[mi] = *(const int32x4*)(Alds + pixm * 256 + c8 + ((qk ^ (pixm & 7)) << 4));
            }
#pragma unroll
            for (int mi = 0; mi < 4; ++mi)
#pragma unroll
                for (int ni = 0; ni < 4; ++ni)
                    acc[mi][ni] = __builtin_amdgcn_mfma_i32_16x16x64_i8(af[mi], bfr[ni * 2 + kk], acc[mi][ni], 0, 0, 0);
        }
    };

    // ---- barrier-free main loop: named double-buffer (rule #20), 1-ahead ----
    int32x4 bA[8], bB[8];
    loadB(0, bA);
#pragma unroll
    for (int ks2 = 0; ks2 < 9; ++ks2) {
        loadB(2 * ks2 + 1, bB);
        step(2 * ks2, bA);
        if (ks2 < 8) loadB(2 * ks2 + 2, bA);
        step(2 * ks2 + 1, bB);
    }

    // -------- epilogue --------
    int co = l & 15;
    int ro = l >> 4;
#pragma unroll
    for (int mi = 0; mi < 4; ++mi) {
#pragma unroll
        for (int ni = 0; ni < 4; ++ni) {
            int n_loc = wc * 64 + ni * 16 + co;
            int o = nb * 128 + n_loc;
            float sc = scale[o];
#pragma unroll
            for (int j = 0; j < 4; ++j) {
                int m_loc = wr * 64 + mi * 16 + ro * 4 + j;
                int h = h0 + (m_loc >> 6);
                int w = m_loc & 63;
                float v = (float)acc[mi][ni][j] * sc;
                if (EPI == 1) {
                    float xv = xaux[((size_t)(b * C_ + o) * H_ + h) * W_ + w];
                    float xr = v + xv;
                    float sv = xr + biasA[o];
                    s2out[((size_t)(b * PH + h + 1) * PW + (w + 1)) * C_ + o] = sign_i8(sv);
                    if (o < NO2)
                        xres_out[(((size_t)b * H_ + h) * W_ + w) * NO2 + o] = xr;
                } else {
                    float xr = xaux[(((size_t)b * H_ + h) * W_ + w) * NO2 + o];
                    float vv = v + xr + biasA[o];
                    vv = (vv >= 0.f) ? vv : vv * slope[o];
                    vv += bias4[o];
                    int p = h & 1, qq = w & 1;
                    dout[(((size_t)b * 512 + (o * 4 + p * 2 + qq)) * 32 + (h >> 1)) * 32 + (w >> 1)] = vv;
                }
            }
        }
    }
}

// distinct names so rocprof disaggregates conv1 vs conv2
__global__ __launch_bounds__(512) void conv_g1(
    const i8* Sin, const i8* Bt, const float* scale, const float* xaux,
    const float* biasA, const float* bias4, const float* slope,
    i8* s2out, float* xres_out, float* dout) {
    extern __shared__ char lds[];
    conv_body<1>(lds, Sin, Bt, scale, xaux, biasA, bias4, slope, s2out, xres_out, dout);
}
__global__ __launch_bounds__(512) void conv_g2(
    const i8* Sin, const i8* Bt, const float* scale, const float* xaux,
    const float* biasA, const float* bias4, const float* slope,
    i8* s2out, float* xres_out, float* dout) {
    extern __shared__ char lds[];
    conv_body<2>(lds, Sin, Bt, scale, xaux, biasA, bias4, slope, s2out, xres_out, dout);
}

// ---------------- workspace layout (bytes, 256-aligned) ----------------
static const size_t SZ_S   = (size_t)B_ * PH * PW * C_;           // 17,842,176 (i8)
static const size_t OFF_S1 = 0;
static const size_t OFF_S2 = OFF_S1 + SZ_S;
static const size_t OFF_B1 = OFF_S2 + SZ_S;                        // 35,684,352
static const size_t OFF_B2 = OFF_B1 + (size_t)NO1 * K1;            // +589,824
static const size_t OFF_C1 = OFF_B2 + (size_t)NO2 * K1;            // +294,912
static const size_t OFF_C2 = OFF_C1 + 1024;
static const size_t OFF_XR = OFF_C2 + 512;                         // ~36.6 MB (256-aligned)

static const int LDS_BYTES = 101376;                               // A tile only

extern "C" void kernel_launch(void* const* d_in, const int* in_sizes, int n_in,
                              void* d_out, int out_size, void* d_ws, size_t ws_size,
                              hipStream_t stream) {
    (void)in_sizes; (void)n_in; (void)out_size; (void)ws_size;
    const float* x      = (const float*)d_in[0];
    const float* w1     = (const float*)d_in[1];
    const float* w2     = (const float*)d_in[2];
    const float* bias1_ = (const float*)d_in[3];
    const float* bias2_ = (const float*)d_in[6];
    const float* bias3  = (const float*)d_in[7];
    const float* bias4  = (const float*)d_in[8];
    const float* ka1    = (const float*)d_in[9];
    const float* kw1    = (const float*)d_in[10];
    const float* ka2    = (const float*)d_in[11];
    const float* kw2    = (const float*)d_in[12];
    const float* slope2 = (const float*)d_in[14];

    char* ws = (char*)d_ws;
    i8*    s1   = (i8*)(ws + OFF_S1);
    i8*    s2   = (i8*)(ws + OFF_S2);
    i8*    Bt1  = (i8*)(ws + OFF_B1);
    i8*    Bt2  = (i8*)(ws + OFF_B2);
    float* sc1  = (float*)(ws + OFF_C1);
    float* sc2  = (float*)(ws + OFF_C2);
    float* xres = (float*)(ws + OFF_XR);
    float* out  = (float*)d_out;

    hipLaunchKernelGGL(prep_s1, dim3(B_ * H_), dim3(256), 0, stream, x, bias1_, s1, s2);
    hipLaunchKernelGGL(prep_w, dim3(NO1 + NO2), dim3(256), 0, stream,
                       w1, w2, ka1, kw1, ka2, kw2, Bt1, Bt2, sc1, sc2);
    hipLaunchKernelGGL(conv_g1, dim3(512), dim3(512), LDS_BYTES, stream,
                       s1, Bt1, sc1, x, bias2_, nullptr, nullptr, s2, xres, nullptr);
    hipLaunchKernelGGL(conv_g2, dim3(256), dim3(512), LDS_BYTES, stream,
                       s2, Bt2, sc2, xres, bias3, bias4, slope2, nullptr, nullptr, out);
}

// Round 12
// 270.868 us; speedup vs baseline: 1.1550x; 1.1550x over previous
//
#include <hip/hip_runtime.h>
#include <hip/hip_bf16.h>
#include <stdint.h>

#define B_   16
#define C_   256
#define H_   64
#define W_   64
#define PH   66
#define PW   66
#define K1   2304   // 256*9
#define NO1  256
#define NO2  128

typedef signed char i8;
typedef int   int32x4 __attribute__((ext_vector_type(4)));

__device__ __forceinline__ void gl_lds16(const void* src, void* dst) {
    __builtin_amdgcn_global_load_lds(
        (const __attribute__((address_space(1))) unsigned int*)src,
        (__attribute__((address_space(3))) unsigned int*)dst, 16, 0, 0);
}

__device__ __forceinline__ i8 sign_i8(float v) {
    return (v > 0.f) ? (i8)1 : ((v < 0.f) ? (i8)(-1) : (i8)0);
}

// ---------------- prep s1: sign(x + bias1_) -> padded NHWC i8 + halo zero -----
// Vectorized: 16 x float4 loads per thread (was 256 scalar f32).
__global__ void prep_s1(const float* __restrict__ x, const float* __restrict__ bias1_,
                        i8* __restrict__ s1, i8* __restrict__ s2) {
    __shared__ i8 tile[64][272];           // [w][c], stride 272 to spread banks
    int b = blockIdx.x >> 6;
    int h = blockIdx.x & 63;
    int t = threadIdx.x;
    int w4 = (t & 15) * 4;                 // w base (4 consecutive)
    int cg = t >> 4;                       // 0..15
    for (int i = 0; i < 16; ++i) {
        int c = i * 16 + cg;
        float4 v = *(const float4*)&x[((size_t)(b * C_ + c) * H_ + h) * W_ + w4];
        float bb = bias1_[c];
        tile[w4 + 0][c] = sign_i8(v.x + bb);
        tile[w4 + 1][c] = sign_i8(v.y + bb);
        tile[w4 + 2][c] = sign_i8(v.z + bb);
        tile[w4 + 3][c] = sign_i8(v.w + bb);
    }
    __syncthreads();
    for (int i = 0; i < 4; ++i) {
        int idx = i * 256 + t;
        int w2  = idx >> 4;                // 16 chunks per pixel
        int cb  = (idx & 15) * 16;
        int4 v = *(const int4*)&tile[w2][cb];
        *(int4*)(s1 + ((size_t)(b * PH + h + 1) * PW + (w2 + 1)) * C_ + cb) = v;
    }
    // ---- halo zeroing ----
    int4 z = make_int4(0, 0, 0, 0);
    if (t < 64) {
        int which = t >> 4;                // 0: s1 c0, 1: s1 c65, 2: s2 c0, 3: s2 c65
        int c16   = t & 15;
        i8* base  = (which < 2) ? s1 : s2;
        int col   = (which & 1) ? 65 : 0;
        *(int4*)(base + ((size_t)(b * PH + h + 1) * PW + col) * C_ + c16 * 16) = z;
    }
    if (h == 0 || h == 63) {
        int prow = (h == 0) ? 0 : 65;
        for (int i = 0; i < 9; ++i) {      // 2 tensors x 1056 chunks = 2112
            int idx = i * 256 + t;
            if (idx < 2112) {
                i8* base = (idx < 1056) ? s1 : s2;
                int k    = (idx < 1056) ? idx : idx - 1056;
                *(int4*)(base + ((size_t)(b * PH + prow) * PW) * C_ + k * 16) = z;
            }
        }
    }
}

// ---------------- prep weights: scale[o] and sign(w) transposed to [n][k] ------
__global__ void prep_w(const float* __restrict__ w1, const float* __restrict__ w2,
                       const float* __restrict__ ka1, const float* __restrict__ kw1,
                       const float* __restrict__ ka2, const float* __restrict__ kw2,
                       i8* __restrict__ Bt1, i8* __restrict__ Bt2,
                       float* __restrict__ scale1, float* __restrict__ scale2) {
    int o = blockIdx.x;
    const float* w; i8* Bt; float* scale; float kk;
    if (o < NO1) { w = w1 + (size_t)o * K1;         Bt = Bt1 + (size_t)o * K1;         scale = scale1 + o;         kk = ka1[0] * kw1[0]; }
    else         { int oo = o - NO1;
                   w = w2 + (size_t)oo * K1;        Bt = Bt2 + (size_t)oo * K1;        scale = scale2 + oo;        kk = ka2[0] * kw2[0]; }
    int t = threadIdx.x;
    float s = 0.f;
    for (int e = t; e < K1; e += 256) {
        float v = w[e];
        s += fabsf(v);
        int c = e / 9, tap = e % 9;
        Bt[tap * 256 + c] = sign_i8(v);
    }
    for (int off = 32; off; off >>= 1) s += __shfl_down(s, off);
    __shared__ float red[4];
    if ((t & 63) == 0) red[t >> 6] = s;
    __syncthreads();
    if (t == 0) {
        float tot = red[0] + red[1] + red[2] + red[3];
        *scale = kk * tot * (1.0f / 2304.0f);
    }
}

// ---------------- A-resident FINE-PHASE binary conv (T2+T3+T4+T5) -------------
// Tile 256x128, 8 waves. A: whole 6x66x256 halo tile (101 KB) LDS-resident
// (one prologue barrier, then read-only). B: triple-buffered 16 KB slots,
// depth-2 counted vmcnt(2) — never drains mid-loop.
// Per K-step, 2 fine phases: {8 ds_reads (af from A, bf from B-cur) || issue 1
// B-stage load -> s_barrier -> setprio(1) 16 MFMA setprio(0) -> s_barrier}.
// The fine interleave (not the coarse stage/compute split of R8) is the
// verified lever (m196/m198/m201). Per-wave vmcnt + barrier at step end =>
// B slot fully landed across all waves before any wave reads it.
template<int EPI>
__device__ __forceinline__ void conv_body(
               char* Alds,
               const i8* __restrict__ Sin, const i8* __restrict__ Bt,
               const float* __restrict__ scale,
               const float* __restrict__ xaux,    // EPI1: x (NCHW f32); EPI2: xres_lo (NHWC 128 f32)
               const float* __restrict__ biasA,   // EPI1: bias2_ ; EPI2: bias3
               const float* __restrict__ bias4,   // EPI2 only
               const float* __restrict__ slope,   // EPI2 only
               i8*   __restrict__ s2out,          // EPI1 only
               float* __restrict__ xres_out,      // EPI1 only
               float* __restrict__ dout)          // EPI2 only
{
    char* Bs0 = Alds + 101376;             // 3 B-slots x 16 KB
    char* Bs1 = Bs0 + 16384;
    char* Bs2 = Bs1 + 16384;

    int t  = threadIdx.x;

    // 1D grid + XCD chunk swizzle (T1): nwg % 8 == 0 -> bijective.
    int wg    = blockIdx.x;
    int chunk = gridDim.x >> 3;
    int logical = (wg & 7) * chunk + (wg >> 3);
    int nb, mb;
    if (EPI == 1) { nb = logical & 1; mb = logical >> 1; }
    else          { nb = 0;           mb = logical; }
    int b  = mb >> 4;
    int h0 = (mb & 15) * 4;        // output rows h0..h0+3

    int l  = t & 63;
    int wv = t >> 6;               // 0..7
    int wr = wv >> 1;              // 0..3 : wave M quarter (64 rows)
    int wc = wv & 1;               // 0..1 : wave N half   (64 cols)
    int q  = l >> 4;               // 0..3 : 16B slot within 64B k-group

    // ---- B staging ----
    int br0  = t >> 3;                                     // row 0..63 (+64)
    int bsrc = ((t & 7) * 16) ^ (((t >> 3) & 7) << 4);     // pre-swizzled source byte
    int blin = (t & 7) * 16;                               // linear LDS dst byte

    auto stageB_half = [&](int ks, char* Bs, int half) {
        int tap = ks >> 1;
        int c0  = (ks & 1) * 128;
        int r   = br0 + half * 64;
        int n   = nb * 128 + r;
        const i8* gb = Bt + (size_t)n * K1 + tap * 256 + c0 + bsrc;
        gl_lds16(gb, Bs + r * 128 + blin);
    };

    // ---- prologue: B(0), B(1), whole A tile ----
    stageB_half(0, Bs0, 0); stageB_half(0, Bs0, 1);
    stageB_half(1, Bs1, 0); stageB_half(1, Bs1, 1);
    for (int i = 0; i < 13; ++i) {
        int idx = i * 512 + t;
        if (idx < 6336) {
            int r6   = idx / 1056;
            int rem  = idx - r6 * 1056;
            int w66  = rem >> 4;
            int slot = rem & 15;
            int pix  = r6 * 66 + w66;
            const i8* ga = Sin + ((size_t)(b * PH + h0 + r6) * PW + w66) * 256
                               + ((slot ^ (pix & 7)) << 4);
            gl_lds16(ga, Alds + idx * 16);
        }
    }
    asm volatile("s_waitcnt vmcnt(0)" ::: "memory");
    __builtin_amdgcn_s_barrier();
    // A read-only from here.

    // ---- per-thread constants ----
    int pixbase[4];
#pragma unroll
    for (int mi = 0; mi < 4; ++mi) {
        int m = wr * 64 + mi * 16 + (l & 15);
        pixbase[mi] = (m >> 6) * 66 + (m & 63);
    }
    int rx = (l & 7) << 4;
    int bfbase[4];
#pragma unroll
    for (int ni = 0; ni < 4; ++ni)
        bfbase[ni] = (wc * 64 + ni * 16 + (l & 15)) * 128;
    int bfoff0 = (q * 16) ^ rx;
    int bfoff1 = (64 + q * 16) ^ rx;

    int32x4 acc[4][4];
#pragma unroll
    for (int mi = 0; mi < 4; ++mi)
#pragma unroll
        for (int ni = 0; ni < 4; ++ni) acc[mi][ni] = (int32x4){0, 0, 0, 0};

    char* pr = Bs0; char* pn = Bs1; char* ps = Bs2;

    for (int ks = 0; ks < 18; ++ks) {
        int tap  = ks >> 1;
        int toff = (tap / 3) * 66 + (tap % 3);
        int c8   = (ks & 1) << 7;

        // ===== phase 0 (kk=0) =====
        {
            int32x4 af[4], bf[4];
#pragma unroll
            for (int mi = 0; mi < 4; ++mi) {
                int pixm = pixbase[mi] + toff;
                af[mi] = *(const int32x4*)(Alds + pixm * 256 + c8 + ((q ^ (pixm & 7)) << 4));
            }
#pragma unroll
            for (int ni = 0; ni < 4; ++ni)
                bf[ni] = *(const int32x4*)(pr + bfbase[ni] + bfoff0);
            if (ks < 16) stageB_half(ks + 2, ps, 0);
            __builtin_amdgcn_s_barrier();
            __builtin_amdgcn_s_setprio(1);
#pragma unroll
            for (int mi = 0; mi < 4; ++mi)
#pragma unroll
                for (int ni = 0; ni < 4; ++ni)
                    acc[mi][ni] = __builtin_amdgcn_mfma_i32_16x16x64_i8(af[mi], bf[ni], acc[mi][ni], 0, 0, 0);
            __builtin_amdgcn_s_setprio(0);
            __builtin_amdgcn_s_barrier();
        }
        // ===== phase 1 (kk=1) =====
        {
            int32x4 af[4], bf[4];
#pragma unroll
            for (int mi = 0; mi < 4; ++mi) {
                int pixm = pixbase[mi] + toff;
                af[mi] = *(const int32x4*)(Alds + pixm * 256 + c8 + (((4 + q) ^ (pixm & 7)) << 4));
            }
#pragma unroll
            for (int ni = 0; ni < 4; ++ni)
                bf[ni] = *(const int32x4*)(pr + bfbase[ni] + bfoff1);
            if (ks < 16) stageB_half(ks + 2, ps, 1);
            __builtin_amdgcn_s_barrier();
            __builtin_amdgcn_s_setprio(1);
#pragma unroll
            for (int mi = 0; mi < 4; ++mi)
#pragma unroll
                for (int ni = 0; ni < 4; ++ni)
                    acc[mi][ni] = __builtin_amdgcn_mfma_i32_16x16x64_i8(af[mi], bf[ni], acc[mi][ni], 0, 0, 0);
            __builtin_amdgcn_s_setprio(0);
            if (ks < 16)       asm volatile("s_waitcnt vmcnt(2)" ::: "memory");  // B(ks+1) landed; B(ks+2) in flight
            else if (ks == 16) asm volatile("s_waitcnt vmcnt(0)" ::: "memory");
            if (ks < 17) __builtin_amdgcn_s_barrier();
        }
        char* tmp = pr; pr = pn; pn = ps; ps = tmp;    // manual 3-rotation (rule #20)
    }

    // -------- epilogue --------
    int co = l & 15;
    int ro = l >> 4;
#pragma unroll
    for (int mi = 0; mi < 4; ++mi) {
#pragma unroll
        for (int ni = 0; ni < 4; ++ni) {
            int n_loc = wc * 64 + ni * 16 + co;
            int o = nb * 128 + n_loc;
            float sc = scale[o];
#pragma unroll
            for (int j = 0; j < 4; ++j) {
                int m_loc = wr * 64 + mi * 16 + ro * 4 + j;
                int h = h0 + (m_loc >> 6);
                int w = m_loc & 63;
                float v = (float)acc[mi][ni][j] * sc;
                if (EPI == 1) {
                    float xv = xaux[((size_t)(b * C_ + o) * H_ + h) * W_ + w];
                    float xr = v + xv;
                    float sv = xr + biasA[o];
                    s2out[((size_t)(b * PH + h + 1) * PW + (w + 1)) * C_ + o] = sign_i8(sv);
                    if (o < NO2)
                        xres_out[(((size_t)b * H_ + h) * W_ + w) * NO2 + o] = xr;
                } else {
                    float xr = xaux[(((size_t)b * H_ + h) * W_ + w) * NO2 + o];
                    float vv = v + xr + biasA[o];
                    vv = (vv >= 0.f) ? vv : vv * slope[o];
                    vv += bias4[o];
                    int p = h & 1, qq = w & 1;
                    dout[(((size_t)b * 512 + (o * 4 + p * 2 + qq)) * 32 + (h >> 1)) * 32 + (w >> 1)] = vv;
                }
            }
        }
    }
}

// distinct names so rocprof disaggregates conv1 vs conv2
__global__ __launch_bounds__(512) void conv_g1(
    const i8* Sin, const i8* Bt, const float* scale, const float* xaux,
    const float* biasA, const float* bias4, const float* slope,
    i8* s2out, float* xres_out, float* dout) {
    extern __shared__ char lds[];
    conv_body<1>(lds, Sin, Bt, scale, xaux, biasA, bias4, slope, s2out, xres_out, dout);
}
__global__ __launch_bounds__(512) void conv_g2(
    const i8* Sin, const i8* Bt, const float* scale, const float* xaux,
    const float* biasA, const float* bias4, const float* slope,
    i8* s2out, float* xres_out, float* dout) {
    extern __shared__ char lds[];
    conv_body<2>(lds, Sin, Bt, scale, xaux, biasA, bias4, slope, s2out, xres_out, dout);
}

// ---------------- workspace layout (bytes, 256-aligned) ----------------
static const size_t SZ_S   = (size_t)B_ * PH * PW * C_;           // 17,842,176 (i8)
static const size_t OFF_S1 = 0;
static const size_t OFF_S2 = OFF_S1 + SZ_S;
static const size_t OFF_B1 = OFF_S2 + SZ_S;                        // 35,684,352
static const size_t OFF_B2 = OFF_B1 + (size_t)NO1 * K1;            // +589,824
static const size_t OFF_C1 = OFF_B2 + (size_t)NO2 * K1;            // +294,912
static const size_t OFF_C2 = OFF_C1 + 1024;
static const size_t OFF_XR = OFF_C2 + 512;                         // ~36.6 MB (256-aligned)

static const int LDS_BYTES = 101376 + 3 * 16384;                   // 150,528

extern "C" void kernel_launch(void* const* d_in, const int* in_sizes, int n_in,
                              void* d_out, int out_size, void* d_ws, size_t ws_size,
                              hipStream_t stream) {
    (void)in_sizes; (void)n_in; (void)out_size; (void)ws_size;
    const float* x      = (const float*)d_in[0];
    const float* w1     = (const float*)d_in[1];
    const float* w2     = (const float*)d_in[2];
    const float* bias1_ = (const float*)d_in[3];
    const float* bias2_ = (const float*)d_in[6];
    const float* bias3  = (const float*)d_in[7];
    const float* bias4  = (const float*)d_in[8];
    const float* ka1    = (const float*)d_in[9];
    const float* kw1    = (const float*)d_in[10];
    const float* ka2    = (const float*)d_in[11];
    const float* kw2    = (const float*)d_in[12];
    const float* slope2 = (const float*)d_in[14];

    char* ws = (char*)d_ws;
    i8*    s1   = (i8*)(ws + OFF_S1);
    i8*    s2   = (i8*)(ws + OFF_S2);
    i8*    Bt1  = (i8*)(ws + OFF_B1);
    i8*    Bt2  = (i8*)(ws + OFF_B2);
    float* sc1  = (float*)(ws + OFF_C1);
    float* sc2  = (float*)(ws + OFF_C2);
    float* xres = (float*)(ws + OFF_XR);
    float* out  = (float*)d_out;

    hipLaunchKernelGGL(prep_s1, dim3(B_ * H_), dim3(256), 0, stream, x, bias1_, s1, s2);
    hipLaunchKernelGGL(prep_w, dim3(NO1 + NO2), dim3(256), 0, stream,
                       w1, w2, ka1, kw1, ka2, kw2, Bt1, Bt2, sc1, sc2);
    hipLaunchKernelGGL(conv_g1, dim3(512), dim3(512), LDS_BYTES, stream,
                       s1, Bt1, sc1, x, bias2_, nullptr, nullptr, s2, xres, nullptr);
    hipLaunchKernelGGL(conv_g2, dim3(256), dim3(512), LDS_BYTES, stream,
                       s2, Bt2, sc2, xres, bias3, bias4, slope2, nullptr, nullptr, out);
}